// Round 1
// baseline (19.947 us; speedup 1.0000x reference)
//
#include <hip/hip_runtime.h>

#define X_DIM 5
#define Y_DIM 2
#define H1 560
#define H2 40
#define GRUH 145
#define GRU3 435

__device__ __forceinline__ float wave_reduce(float v) {
#pragma unroll
    for (int off = 32; off > 0; off >>= 1)
        v += __shfl_xor(v, off, 64);
    return v;
}

__device__ __forceinline__ float sigmoidf_(float x) {
    return 1.0f / (1.0f + __expf(-x));
}

// K1: blocks [0,37): h0 elements (4 waves/block, wave-per-element; each block
//     redundantly computes x (14) and l1_out (560) in LDS first).
//     blocks [37,146): gh1 = Whh1 @ hn[1] + bhh1 (wave-per-row, 4 rows/block).
__global__ __launch_bounds__(256) void k1_gru0(
    const float* __restrict__ si, const float* __restrict__ oi,
    const float* __restrict__ dst, const float* __restrict__ dob,
    const float* __restrict__ W1, const float* __restrict__ b1,
    const float* __restrict__ Wih0, const float* __restrict__ Whh0,
    const float* __restrict__ bih0, const float* __restrict__ bhh0,
    const float* __restrict__ Whh1, const float* __restrict__ bhh1,
    const float* __restrict__ hn,
    float* __restrict__ h0_out, float* __restrict__ gh1_out)
{
    const int NB_H0 = 37;
    const int tid = threadIdx.x;
    const int wid = tid >> 6, lane = tid & 63;

    if (blockIdx.x < NB_H0) {
        __shared__ float x[16];
        __shared__ float l1[H1];
        if (tid < X_DIM)                      x[tid] = si[tid];
        else if (tid < X_DIM + Y_DIM)         x[tid] = oi[tid - X_DIM];
        else if (tid < 2 * X_DIM + Y_DIM)     x[tid] = dst[tid - X_DIM - Y_DIM];
        else if (tid < 2 * X_DIM + 2 * Y_DIM) x[tid] = dob[tid - 2 * X_DIM - Y_DIM];
        __syncthreads();

        for (int j = tid; j < H1; j += 256) {
            float a = b1[j];
            const float* w = W1 + j * 14;
#pragma unroll
            for (int k = 0; k < 14; ++k) a = fmaf(w[k], x[k], a);
            l1[j] = fmaxf(a, 0.0f);
        }
        __syncthreads();

        const int i = blockIdx.x * 4 + wid;
        if (i < GRUH) {
            const float* hn0 = hn;
            float air = 0.f, aiz = 0.f, ain = 0.f;
            float ahr = 0.f, ahz = 0.f, ahn = 0.f;
            for (int k = lane; k < H1; k += 64) {
                const float lv = l1[k];
                air = fmaf(Wih0[(i        ) * H1 + k], lv, air);
                aiz = fmaf(Wih0[(i + GRUH ) * H1 + k], lv, aiz);
                ain = fmaf(Wih0[(i + 2*GRUH) * H1 + k], lv, ain);
            }
            for (int k = lane; k < GRUH; k += 64) {
                const float hv = hn0[k];
                ahr = fmaf(Whh0[(i        ) * GRUH + k], hv, ahr);
                ahz = fmaf(Whh0[(i + GRUH ) * GRUH + k], hv, ahz);
                ahn = fmaf(Whh0[(i + 2*GRUH) * GRUH + k], hv, ahn);
            }
            air = wave_reduce(air); aiz = wave_reduce(aiz); ain = wave_reduce(ain);
            ahr = wave_reduce(ahr); ahz = wave_reduce(ahz); ahn = wave_reduce(ahn);
            if (lane == 0) {
                const float ir = air + bih0[i];
                const float iz = aiz + bih0[i + GRUH];
                const float in_ = ain + bih0[i + 2*GRUH];
                const float hr = ahr + bhh0[i];
                const float hz = ahz + bhh0[i + GRUH];
                const float hnv = ahn + bhh0[i + 2*GRUH];
                const float r = sigmoidf_(ir + hr);
                const float z = sigmoidf_(iz + hz);
                const float n = tanhf(in_ + r * hnv);
                h0_out[i] = (1.0f - z) * n + z * hn0[i];
            }
        }
    } else {
        const int row = (blockIdx.x - NB_H0) * 4 + wid;
        if (row < GRU3) {
            const float* hn1 = hn + GRUH;
            float a = 0.f;
            for (int k = lane; k < GRUH; k += 64)
                a = fmaf(Whh1[row * GRUH + k], hn1[k], a);
            a = wave_reduce(a);
            if (lane == 0) gh1_out[row] = a + bhh1[row];
        }
    }
}

// K2: gi1 = Wih1 @ h0 + bih1, combine with gh1 -> h1 (wave-per-element).
__global__ __launch_bounds__(256) void k2_gru1(
    const float* __restrict__ Wih1, const float* __restrict__ bih1,
    const float* __restrict__ hn,
    const float* __restrict__ h0, const float* __restrict__ gh1,
    float* __restrict__ h1_out)
{
    __shared__ float h0s[GRUH];
    const int tid = threadIdx.x;
    const int wid = tid >> 6, lane = tid & 63;
    if (tid < GRUH) h0s[tid] = h0[tid];
    __syncthreads();

    const int i = blockIdx.x * 4 + wid;
    if (i < GRUH) {
        float air = 0.f, aiz = 0.f, ain = 0.f;
        for (int k = lane; k < GRUH; k += 64) {
            const float hv = h0s[k];
            air = fmaf(Wih1[(i        ) * GRUH + k], hv, air);
            aiz = fmaf(Wih1[(i + GRUH ) * GRUH + k], hv, aiz);
            ain = fmaf(Wih1[(i + 2*GRUH) * GRUH + k], hv, ain);
        }
        air = wave_reduce(air); aiz = wave_reduce(aiz); ain = wave_reduce(ain);
        if (lane == 0) {
            const float* hn1 = hn + GRUH;
            const float ir = air + bih1[i];
            const float iz = aiz + bih1[i + GRUH];
            const float in_ = ain + bih1[i + 2*GRUH];
            const float hr = gh1[i];
            const float hz = gh1[i + GRUH];
            const float hnv = gh1[i + 2*GRUH];
            const float r = sigmoidf_(ir + hr);
            const float z = sigmoidf_(iz + hz);
            const float n = tanhf(in_ + r * hnv);
            h1_out[i] = (1.0f - z) * n + z * hn1[i];
        }
    }
}

// K3: l2_hidden = relu(W2a@h1 + b2a); out = W2b@l2_hidden + b2b. One block.
__global__ __launch_bounds__(256) void k3_head(
    const float* __restrict__ W2a, const float* __restrict__ b2a,
    const float* __restrict__ W2b, const float* __restrict__ b2b,
    const float* __restrict__ h1, float* __restrict__ out)
{
    __shared__ float h1s[GRUH];
    __shared__ float l2h[H2];
    const int tid = threadIdx.x;
    const int wid = tid >> 6, lane = tid & 63;
    if (tid < GRUH) h1s[tid] = h1[tid];
    __syncthreads();

    for (int row = wid; row < H2; row += 4) {
        float a = 0.f;
        for (int k = lane; k < GRUH; k += 64)
            a = fmaf(W2a[row * GRUH + k], h1s[k], a);
        a = wave_reduce(a);
        if (lane == 0) l2h[row] = fmaxf(a + b2a[row], 0.0f);
    }
    __syncthreads();

    if (tid < X_DIM * Y_DIM) {
        float a = b2b[tid];
#pragma unroll
        for (int k = 0; k < H2; ++k)
            a = fmaf(W2b[tid * H2 + k], l2h[k], a);
        out[tid] = a;
    }
}

extern "C" void kernel_launch(void* const* d_in, const int* in_sizes, int n_in,
                              void* d_out, int out_size, void* d_ws, size_t ws_size,
                              hipStream_t stream) {
    const float* si   = (const float*)d_in[0];
    const float* oi   = (const float*)d_in[1];
    const float* dst  = (const float*)d_in[2];
    const float* dob  = (const float*)d_in[3];
    const float* W1   = (const float*)d_in[4];
    const float* b1   = (const float*)d_in[5];
    const float* Wih0 = (const float*)d_in[6];
    const float* Whh0 = (const float*)d_in[7];
    const float* bih0 = (const float*)d_in[8];
    const float* bhh0 = (const float*)d_in[9];
    const float* Wih1 = (const float*)d_in[10];
    const float* Whh1 = (const float*)d_in[11];
    const float* bih1 = (const float*)d_in[12];
    const float* bhh1 = (const float*)d_in[13];
    const float* W2a  = (const float*)d_in[14];
    const float* b2a  = (const float*)d_in[15];
    const float* W2b  = (const float*)d_in[16];
    const float* b2b  = (const float*)d_in[17];
    const float* hn   = (const float*)d_in[18];

    float* ws  = (float*)d_ws;
    float* h0  = ws;            // 145
    float* gh1 = ws + GRUH;     // 435
    float* h1  = ws + GRUH + GRU3; // 145

    hipLaunchKernelGGL(k1_gru0, dim3(146), dim3(256), 0, stream,
                       si, oi, dst, dob, W1, b1, Wih0, Whh0, bih0, bhh0,
                       Whh1, bhh1, hn, h0, gh1);
    hipLaunchKernelGGL(k2_gru1, dim3(37), dim3(256), 0, stream,
                       Wih1, bih1, hn, h0, gh1, h1);
    hipLaunchKernelGGL(k3_head, dim3(1), dim3(256), 0, stream,
                       W2a, b2a, W2b, b2b, h1, (float*)d_out);
}